// Round 13
// baseline (182.437 us; speedup 1.0000x reference)
//
#include <hip/hip_runtime.h>
#include <hip/hip_bf16.h>

#define Bn  2
#define Sn  2048
#define Hn  1024
#define NHn 16
#define DHn 64
#define Mn  (Bn * Sn)   // 4096 rows of X

typedef __attribute__((ext_vector_type(4)))  float    f32x4;
typedef __attribute__((ext_vector_type(16))) float    f32x16;
typedef __attribute__((ext_vector_type(8)))  _Float16 h8;
typedef __attribute__((ext_vector_type(4)))  _Float16 h4;
typedef __attribute__((ext_vector_type(2)))  __fp16   fp16x2;
typedef __attribute__((ext_vector_type(2)))  unsigned int u32x2;

union H2PK { fp16x2 v; unsigned int u; };
union U4H8 { unsigned int u[4]; h8 v; };

#define MFMA16F(a, b, c) __builtin_amdgcn_mfma_f32_16x16x32_f16(a, b, c, 0, 0, 0)
#define MFMA32F(a, b, c) __builtin_amdgcn_mfma_f32_32x32x16_f16(a, b, c, 0, 0, 0)

// score scale 0.125 (=1/sqrt(64)) pre-multiplied by log2(e), folded into Qh
#define SCFULL 0.18033688011112042f
#define L2E    1.44269504088896340736f

// async global->LDS: LDS dest = wave-uniform base + lane*16 (m104)
__device__ __forceinline__ void glds16(const void* g, void* l) {
    __builtin_amdgcn_global_load_lds(
        (const __attribute__((address_space(1))) unsigned int*)g,
        (__attribute__((address_space(3))) unsigned int*)l, 16, 0, 0);
}

// ---------------------------------------------------------------------------
// Fused prepass: blocks [0,4096) convert X fp32->fp16; [4096,4864) transpose
// one 64x64 W tile; block 4864 computes Wm[k] = e^mask (fp16).
// (unchanged from round 12)
// ---------------------------------------------------------------------------
__global__ __launch_bounds__(256) void prep(
    const float* __restrict__ X, const float* __restrict__ W0,
    const float* __restrict__ W1, const float* __restrict__ W2,
    const float* __restrict__ Msk,
    _Float16* __restrict__ Xh, _Float16* __restrict__ WT,
    _Float16* __restrict__ Wm)
{
    const int bid = blockIdx.x;
    const int tid = threadIdx.x;
    __shared__ float Ws[64][65];

    if (bid < 4096) {
        const int i = bid * 256 + tid;   // over Mn*Hn/4 float4s
        float4 x = ((const float4*)X)[i];
        h4 o;
        o[0] = (_Float16)x.x; o[1] = (_Float16)x.y;
        o[2] = (_Float16)x.z; o[3] = (_Float16)x.w;
        *(h4*)&Xh[(size_t)i * 4] = o;
        return;
    }
    if (bid >= 4096 + 768) {
#pragma unroll
        for (int it = 0; it < 16; ++it) {
            const int idx = it * 256 + tid;
            Wm[idx] = (_Float16)__builtin_amdgcn_exp2f(Msk[idx] * L2E);
        }
        return;
    }

    const int wb = bid - 4096;              // 0..767
    const int which = wb >> 8;              // 0..2
    const int rem = wb & 255;
    const int k0 = ((rem >> 4) & 15) * 64;
    const int n0 = (rem & 15) * 64;
    const float* W = (which == 0) ? W0 : (which == 1 ? W1 : W2);
    _Float16* O = WT + (size_t)which * Hn * Hn;

#pragma unroll
    for (int it = 0; it < 4; ++it) {
        const int idx = tid + 256 * it;
        const int row = idx >> 4, c4 = (idx & 15) * 4;
        float4 w = *(const float4*)&W[(size_t)(k0 + row) * Hn + n0 + c4];
        Ws[row][c4 + 0] = w.x; Ws[row][c4 + 1] = w.y;
        Ws[row][c4 + 2] = w.z; Ws[row][c4 + 3] = w.w;
    }
    __syncthreads();
#pragma unroll
    for (int it = 0; it < 16; ++it) {
        const int e = tid + 256 * it;
        const int k = e & 63, n = e >> 6;
        O[(size_t)(n0 + n) * Hn + k0 + k] = (_Float16)Ws[k][n];
    }
}

// ---------------------------------------------------------------------------
// QKV projection, fp16 MFMA, 128x128 tile, 4 waves (2x2).
// Round-13: port attn's PROVEN pipeline (4 rounds of evidence, 47.6us attn):
// BK=32, 3 LDS buffers (48KB -> 3 blocks/CU preserved), one barrier/K-step,
// counted vmcnt(4) (tile kt landed, kt+1's 4 glds stay in flight with ~2
// iterations of slack), stage(kt+2) issued AFTER the barrier (race-free:
// all waves passed barrier kt => all finished compute(kt-1), the previous
// reader of buf (kt+2)%3). Replaces the 16 full vmcnt(0) drains of the
// round-7 drain structure with exactly 1 (final step).
// which==0 (Q): epilogue x SCFULL. which==2 (V): epilogue x Wm[key].
// ---------------------------------------------------------------------------
__global__ __launch_bounds__(256) void qkv_mfma(
    const _Float16* __restrict__ Xh, const _Float16* __restrict__ WTA,
    const float* __restrict__ b0, const float* __restrict__ b1,
    const float* __restrict__ b2, const _Float16* __restrict__ Wm,
    _Float16* __restrict__ Qh, _Float16* __restrict__ Kh,
    _Float16* __restrict__ VTh)
{
    const int which = blockIdx.z;
    const _Float16* WT = WTA + (size_t)which * Hn * Hn;
    const float* bias = (which == 0) ? b0 : (which == 1 ? b1 : b2);
    _Float16* Dst = (which == 0) ? Qh : (which == 1 ? Kh : VTh);

    const int m0 = blockIdx.x * 128;
    const int n0 = blockIdx.y * 128;
    const int tid  = threadIdx.x;
    const int wid  = tid >> 6;
    const int lane = tid & 63;
    const int l16  = lane & 15;
    const int quad = lane >> 4;
    const int wm = wid >> 1, wn = wid & 1;

    __shared__ __align__(16) _Float16 Ah[3][4096], Bh[3][4096];   // 48 KB

    f32x4 acc[4][4];
#pragma unroll
    for (int i = 0; i < 4; ++i)
#pragma unroll
        for (int j = 0; j < 4; ++j) acc[i][j] = (f32x4){0.f, 0.f, 0.f, 0.f};

    // stage one BK=32 tile pair: 4 glds16/thread (A x2, B x2).
    // rows are 64B = 4 chunks; chunk c stored at c^(row&3) (global side).
    auto stage = [&](int kt, int buf) {
        const int k0 = kt * 32;
#pragma unroll
        for (int c = 0; c < 2; ++c) {
            const int idx = (wid * 2 + c) * 64 + lane;   // chunk id 0..511
            const int row = idx >> 2;
            const int cg  = (idx & 3) ^ (row & 3);
            glds16(&Xh[(size_t)(m0 + row) * Hn + k0 + cg * 8],
                   &Ah[buf][(wid * 2 + c) * 512]);
            glds16(&WT[(size_t)(n0 + row) * Hn + k0 + cg * 8],
                   &Bh[buf][(wid * 2 + c) * 512]);
        }
    };

    stage(0, 0);
    stage(1, 1);

    for (int kt = 0; kt < 32; ++kt) {   // 32 K-steps of 32
        if (kt < 31) asm volatile("s_waitcnt vmcnt(4)" ::: "memory");
        else         asm volatile("s_waitcnt vmcnt(0)" ::: "memory");
        __builtin_amdgcn_s_barrier();
        asm volatile("" ::: "memory");
        if (kt + 2 < 32) stage(kt + 2, (kt + 2) % 3);

        const int buf = kt % 3;
        h8 xa[4], wb[4];
#pragma unroll
        for (int t = 0; t < 4; ++t) {
            const int ar = wm * 64 + t * 16 + l16;
            const int br = wn * 64 + t * 16 + l16;
            xa[t] = *(const h8*)&Ah[buf][ar * 32 + ((quad ^ (ar & 3)) * 8)];
            wb[t] = *(const h8*)&Bh[buf][br * 32 + ((quad ^ (br & 3)) * 8)];
        }
        if (which < 2) {
#pragma unroll
            for (int i = 0; i < 4; ++i)
#pragma unroll
                for (int j = 0; j < 4; ++j)
                    acc[i][j] = MFMA16F(xa[i], wb[j], acc[i][j]);
        } else {
#pragma unroll
            for (int i = 0; i < 4; ++i)
#pragma unroll
                for (int j = 0; j < 4; ++j)
                    acc[i][j] = MFMA16F(wb[i], xa[j], acc[i][j]);
        }
    }

    const float oscale = (which == 0) ? SCFULL : 1.0f;
    if (which < 2) {
        // D[m=quad*4+r][n=l16] -> [bh][s][d]
#pragma unroll
        for (int j = 0; j < 4; ++j) {
            const int n = n0 + wn * 64 + j * 16 + l16;
            const float bv = bias[n];
            const int hh = n >> 6, dd = n & 63;
#pragma unroll
            for (int i = 0; i < 4; ++i) {
                const int mb = m0 + wm * 64 + i * 16 + quad * 4;
#pragma unroll
                for (int r = 0; r < 4; ++r) {
                    const int m = mb + r;
                    const int b = m >> 11, s = m & (Sn - 1);
                    Dst[(((size_t)b * NHn + hh) * Sn + s) * DHn + dd] =
                        (_Float16)((acc[i][j][r] + bv) * oscale);
                }
            }
        }
    } else {
        // swapped: D rows = n-dim, cols = m-dim -> [bh][d][s]; x Wm[key=m]
        float wvj[4];
#pragma unroll
        for (int j = 0; j < 4; ++j)
            wvj[j] = (float)Wm[m0 + wm * 64 + j * 16 + l16];
#pragma unroll
        for (int i = 0; i < 4; ++i) {
#pragma unroll
            for (int r = 0; r < 4; ++r) {
                const int n = n0 + wn * 64 + i * 16 + quad * 4 + r;
                const float bv = bias[n];
                const int hh = n >> 6, dd = n & 63;
#pragma unroll
                for (int j = 0; j < 4; ++j) {
                    const int m = m0 + wm * 64 + j * 16 + l16;
                    const int b = m >> 11, s = m & (Sn - 1);
                    Dst[(((size_t)b * NHn + hh) * DHn + dd) * Sn + s] =
                        (_Float16)((acc[i][j][r] + bv) * wvj[j]);
                }
            }
        }
    }
}

// ---------------------------------------------------------------------------
// Flash attention (round-12 structure, UNCHANGED — best at 47.6us).
// ---------------------------------------------------------------------------
__global__ __launch_bounds__(256, 2) void attn(
    const _Float16* __restrict__ Qh, const _Float16* __restrict__ Kh,
    const _Float16* __restrict__ VTh, const _Float16* __restrict__ Wmg,
    float* __restrict__ Out)
{
    // --- XCD-grouping remap: 512 blocks, 8 XCDs, 4 bh per XCD ---
    const int flat = blockIdx.x + 16 * blockIdx.y + 256 * blockIdx.z;
    const int bh   = ((flat & 7) << 2) | ((flat >> 3) & 3);  // 0..31
    const int qb   = flat >> 5;                              // 0..15
    const int b = bh >> 4, h = bh & 15;

    const int tid  = threadIdx.x;
    const int wid  = tid >> 6;
    const int lane = tid & 63;
    const int l32  = lane & 31;
    const int hi   = lane >> 5;

    __shared__ __align__(16) _Float16 Kb[4][4096];  // [key][dim], swizzled
    __shared__ __align__(16) _Float16 Vb[4][4096];  // [dim][key], swizzled
    __shared__ __align__(16) _Float16 Wbs[Sn];      // full w row (4KB), once

    const int q0 = qb * 128 + wid * 32;

    const _Float16* Kg = Kh  + (size_t)bh * Sn * DHn;   // [key][dim]
    const _Float16* Vg = VTh + (size_t)bh * DHn * Sn;   // [dim][key]
    const _Float16* Wg = Wmg + (size_t)b * Sn;          // [key] weights

    // one-time W stage: 256 threads x 16B = 4KB (wave wid covers 512 elems)
    glds16(&Wg[(wid * 64 + lane) * 8], &Wbs[wid * 512]);

    const size_t qbase = ((size_t)bh * Sn + q0 + l32) * DHn;
    h8 qf[4];   // B-frag: B[k=dim][n=q=l32]
#pragma unroll
    for (int kd = 0; kd < 4; ++kd)
        qf[kd] = *(const h8*)&Qh[qbase + kd * 16 + hi * 8];

    asm volatile("s_waitcnt vmcnt(0)" ::: "memory");   // qf + W done, counter clean

    // stage one 64-key tile (4 glds16 per thread: K0,V0,K1,V1)
    auto stage = [&](int kt, int buf) {
        const int koff = kt * 64;
#pragma unroll
        for (int c = 0; c < 2; ++c) {
            const int idx = (wid * 2 + c) * 64 + lane;
            const int row = idx >> 3;
            const int cg  = (idx & 7) ^ (row & 7);
            glds16(&Kg[(size_t)(koff + row) * DHn + cg * 8],
                   &Kb[buf][(wid * 2 + c) * 512]);
            glds16(&Vg[(size_t)row * Sn + koff + cg * 8],
                   &Vb[buf][(wid * 2 + c) * 512]);
        }
    };

    stage(0, 0);
    stage(1, 1);

    f32x16 sA[2], sB[2], o[2], acc_l;
#pragma unroll
    for (int dt = 0; dt < 2; ++dt) o[dt] = (f32x16)(0.f);
    acc_l = (f32x16)(0.f);

    // D = K.Q^T for one 64-key tile -> s[2]; C init = 0
    auto qkt = [&](f32x16 (&s)[2], int buf) {
        __builtin_amdgcn_s_setprio(1);
#pragma unroll
        for (int t = 0; t < 2; ++t) {
            f32x16 c = (f32x16)(0.f);
#pragma unroll
            for (int kd = 0; kd < 4; ++kd) {
                const int row = t * 32 + l32;   // A-frag: A[m=key=row][k=dim]
                h8 kf = *(const h8*)&Kb[buf][row * 64 +
                                             (((kd * 2 + hi) ^ (row & 7)) * 8)];
                c = MFMA32F(kf, qf[kd], c);
            }
            s[t] = c;
        }
        __builtin_amdgcn_s_setprio(0);
    };

    // softmax from s, permlane exchange + PV + l-MFMA (w from one-time LDS)
    auto sm_pv = [&](f32x16 (&s)[2], int ktile, int buf) {
        unsigned int pk[2][4][2];
#pragma unroll
        for (int t = 0; t < 2; ++t) {
#pragma unroll
            for (int g = 0; g < 4; ++g) {
                const float p0 = __builtin_amdgcn_exp2f(s[t][g * 4 + 0]);
                const float p1 = __builtin_amdgcn_exp2f(s[t][g * 4 + 1]);
                const float p2 = __builtin_amdgcn_exp2f(s[t][g * 4 + 2]);
                const float p3 = __builtin_amdgcn_exp2f(s[t][g * 4 + 3]);
                H2PK u0, u1;
                u0.v = __builtin_amdgcn_cvt_pkrtz(p0, p1);
                u1.v = __builtin_amdgcn_cvt_pkrtz(p2, p3);
                pk[t][g][0] = u0.u;
                pk[t][g][1] = u1.u;
            }
        }

        __builtin_amdgcn_s_setprio(1);
#pragma unroll
        for (int ks = 0; ks < 4; ++ks) {
            const int t = ks >> 1, ge = (ks & 1) * 2;   // ge feeds dest hi=0
            u32x2 rA = __builtin_amdgcn_permlane32_swap(
                pk[t][ge][0], pk[t][ge + 1][0], false, false);
            u32x2 rB = __builtin_amdgcn_permlane32_swap(
                pk[t][ge][1], pk[t][ge + 1][1], false, false);
            U4H8 w;
            w.u[0] = rA[0]; w.u[1] = rB[0]; w.u[2] = rA[1]; w.u[3] = rB[1];
            // l: B[k][n] = w[key] broadcast over n
            h8 wv8 = *(const h8*)&Wbs[ktile * 64 + ks * 16 + hi * 8];
            acc_l = MFMA32F(w.v, wv8, acc_l);
#pragma unroll
            for (int dt = 0; dt < 2; ++dt) {
                const int row = dt * 32 + l32;   // B-frag: B[k=key][n=dim=row]
                h8 vf = *(const h8*)&Vb[buf][row * 64 +
                                             (((ks * 2 + hi) ^ (row & 7)) * 8)];
                o[dt] = MFMA32F(w.v, vf, o[dt]);
            }
        }
        __builtin_amdgcn_s_setprio(0);
    };

    // prologue: tile0 resident -> scores(0) into sA
    asm volatile("s_waitcnt vmcnt(4)" ::: "memory");
    __builtin_amdgcn_s_barrier();
    asm volatile("" ::: "memory");
    qkt(sA, 0);

    auto iter = [&](int kt, f32x16 (&scur)[2], f32x16 (&snxt)[2]) {
        stage(kt + 2, (kt + 2) & 3);
        asm volatile("s_waitcnt vmcnt(4)" ::: "memory");  // tile kt+1 landed
        __builtin_amdgcn_s_barrier();
        asm volatile("" ::: "memory");
        qkt(snxt, (kt + 1) & 3);       // MFMA, overlaps softmax below
        sm_pv(scur, kt, kt & 3);       // VALU + PV MFMA
    };

    for (int kt = 0; kt < 30; kt += 2) {
        iter(kt,     sA, sB);
        iter(kt + 1, sB, sA);
    }
    // kt = 30: no more staging; tile 31 needs full drain
    asm volatile("s_waitcnt vmcnt(0)" ::: "memory");
    __builtin_amdgcn_s_barrier();
    asm volatile("" ::: "memory");
    qkt(sB, 31 & 3);
    sm_pv(sA, 30, 30 & 3);
    sm_pv(sB, 31, 31 & 3);

    // ---- final: per-lane l (same C/D row mapping as o), normalize, store ----
#pragma unroll
    for (int g2 = 0; g2 < 4; ++g2) {
#pragma unroll
        for (int e = 0; e < 4; ++e) {
            const int r = g2 * 4 + e;
            const int q = q0 + 4 * hi + 8 * g2 + e;   // C/D row formula
            const size_t ob = ((size_t)b * Sn + q) * Hn + h * DHn;
            const float sc = 1.0f / acc_l[r];
#pragma unroll
            for (int dt = 0; dt < 2; ++dt)
                Out[ob + dt * 32 + l32] = o[dt][r] * sc;
        }
    }
}

extern "C" void kernel_launch(void* const* d_in, const int* in_sizes, int n_in,
                              void* d_out, int out_size, void* d_ws, size_t ws_size,
                              hipStream_t stream) {
    const float* X    = (const float*)d_in[0];
    const float* mask = (const float*)d_in[1];
    const float* Wq   = (const float*)d_in[2];
    const float* bq   = (const float*)d_in[3];
    const float* Wk   = (const float*)d_in[4];
    const float* bk   = (const float*)d_in[5];
    const float* Wv   = (const float*)d_in[6];
    const float* bv   = (const float*)d_in[7];
    float* out = (float*)d_out;

    const size_t NE = (size_t)Mn * Hn;         // 4M elements
    _Float16* Xh  = (_Float16*)d_ws;           // 8 MB
    _Float16* WT  = Xh + NE;                   // 3 x 2 MB
    _Float16* Qh  = WT + (size_t)3 * Hn * Hn;  // 8 MB
    _Float16* Kh  = Qh + NE;                   // 8 MB
    _Float16* VTh = Kh + NE;                   // 8 MB
    _Float16* Wm  = VTh + NE;                  // 4096 + 512 pad (glds overrun)

    prep<<<dim3(4096 + 768 + 1), dim3(256), 0, stream>>>(
        X, Wq, Wk, Wv, mask, Xh, WT, Wm);

    dim3 g1(Mn / 128, Hn / 128, 3), b1(256);
    qkv_mfma<<<g1, b1, 0, stream>>>(Xh, WT, bq, bk, bv, Wm, Qh, Kh, VTh);

    dim3 g2(Sn / 128, NHn, Bn), b2(256);
    attn<<<g2, b2, 0, stream>>>(Qh, Kh, VTh, Wm, out);
}

// Round 14
// 166.297 us; speedup vs baseline: 1.0971x; 1.0971x over previous
//
#include <hip/hip_runtime.h>
#include <hip/hip_bf16.h>

#define Bn  2
#define Sn  2048
#define Hn  1024
#define NHn 16
#define DHn 64
#define Mn  (Bn * Sn)   // 4096 rows of X

typedef __attribute__((ext_vector_type(4)))  float    f32x4;
typedef __attribute__((ext_vector_type(16))) float    f32x16;
typedef __attribute__((ext_vector_type(8)))  _Float16 h8;
typedef __attribute__((ext_vector_type(4)))  _Float16 h4;
typedef __attribute__((ext_vector_type(2)))  __fp16   fp16x2;
typedef __attribute__((ext_vector_type(2)))  unsigned int u32x2;

union H2PK { fp16x2 v; unsigned int u; };
union U4H8 { unsigned int u[4]; h8 v; };

#define MFMA16F(a, b, c) __builtin_amdgcn_mfma_f32_16x16x32_f16(a, b, c, 0, 0, 0)
#define MFMA32F(a, b, c) __builtin_amdgcn_mfma_f32_32x32x16_f16(a, b, c, 0, 0, 0)

// score scale 0.125 (=1/sqrt(64)) pre-multiplied by log2(e), folded into Qh
#define SCFULL 0.18033688011112042f
#define L2E    1.44269504088896340736f

// async global->LDS: LDS dest = wave-uniform base + lane*16 (m104)
__device__ __forceinline__ void glds16(const void* g, void* l) {
    __builtin_amdgcn_global_load_lds(
        (const __attribute__((address_space(1))) unsigned int*)g,
        (__attribute__((address_space(3))) unsigned int*)l, 16, 0, 0);
}

// ---------------------------------------------------------------------------
// Fused prepass: blocks [0,2048) convert X fp32->fp16 (2 float4/thread);
// [2048,2816) transpose one 64x64 W tile; block 2816 computes Wm[k] = e^mask.
// ---------------------------------------------------------------------------
__global__ __launch_bounds__(256) void prep(
    const float* __restrict__ X, const float* __restrict__ W0,
    const float* __restrict__ W1, const float* __restrict__ W2,
    const float* __restrict__ Msk,
    _Float16* __restrict__ Xh, _Float16* __restrict__ WT,
    _Float16* __restrict__ Wm)
{
    const int bid = blockIdx.x;
    const int tid = threadIdx.x;
    __shared__ float Ws[64][65];

    if (bid < 2048) {
#pragma unroll
        for (int r = 0; r < 2; ++r) {
            const int i = bid * 512 + r * 256 + tid;   // over Mn*Hn/4 float4s
            float4 x = ((const float4*)X)[i];
            h4 o;
            o[0] = (_Float16)x.x; o[1] = (_Float16)x.y;
            o[2] = (_Float16)x.z; o[3] = (_Float16)x.w;
            *(h4*)&Xh[(size_t)i * 4] = o;
        }
        return;
    }
    if (bid >= 2048 + 768) {
#pragma unroll
        for (int it = 0; it < 16; ++it) {
            const int idx = it * 256 + tid;
            Wm[idx] = (_Float16)__builtin_amdgcn_exp2f(Msk[idx] * L2E);
        }
        return;
    }

    const int wb = bid - 2048;              // 0..767
    const int which = wb >> 8;              // 0..2
    const int rem = wb & 255;
    const int k0 = ((rem >> 4) & 15) * 64;
    const int n0 = (rem & 15) * 64;
    const float* W = (which == 0) ? W0 : (which == 1 ? W1 : W2);
    _Float16* O = WT + (size_t)which * Hn * Hn;

#pragma unroll
    for (int it = 0; it < 4; ++it) {
        const int idx = tid + 256 * it;
        const int row = idx >> 4, c4 = (idx & 15) * 4;
        float4 w = *(const float4*)&W[(size_t)(k0 + row) * Hn + n0 + c4];
        Ws[row][c4 + 0] = w.x; Ws[row][c4 + 1] = w.y;
        Ws[row][c4 + 2] = w.z; Ws[row][c4 + 3] = w.w;
    }
    __syncthreads();
#pragma unroll
    for (int it = 0; it < 16; ++it) {
        const int e = tid + 256 * it;
        const int k = e & 63, n = e >> 6;
        O[(size_t)(n0 + n) * Hn + k0 + k] = (_Float16)Ws[k][n];
    }
}

// ---------------------------------------------------------------------------
// QKV projection, fp16 MFMA, 128x128 tile, BK=64, drain structure (round 7).
// Round-14: REVERTED to this after the round-13 counted-vmcnt port regressed
// (58.6us vs ~46): qkv's compute phase is LDS-read-dense (16 ds_read_b128 :
// 32 MFMA), so overlapped glds WRITES steal critical-pipe bandwidth; in the
// drain structure writes land while waves idle at the barrier (free).
// Pipelining pays only with LDS slack in compute — attn yes, qkv no.
// which==0 (Q): epilogue x SCFULL. which==2 (V): epilogue x Wm[key].
// ---------------------------------------------------------------------------
__global__ __launch_bounds__(256) void qkv_mfma(
    const _Float16* __restrict__ Xh, const _Float16* __restrict__ WTA,
    const float* __restrict__ b0, const float* __restrict__ b1,
    const float* __restrict__ b2, const _Float16* __restrict__ Wm,
    _Float16* __restrict__ Qh, _Float16* __restrict__ Kh,
    _Float16* __restrict__ VTh)
{
    const int which = blockIdx.z;
    const _Float16* WT = WTA + (size_t)which * Hn * Hn;
    const float* bias = (which == 0) ? b0 : (which == 1 ? b1 : b2);
    _Float16* Dst = (which == 0) ? Qh : (which == 1 ? Kh : VTh);

    const int m0 = blockIdx.x * 128;
    const int n0 = blockIdx.y * 128;
    const int tid  = threadIdx.x;
    const int wid  = tid >> 6;
    const int lane = tid & 63;
    const int l16  = lane & 15;
    const int quad = lane >> 4;
    const int wm = wid >> 1, wn = wid & 1;

    __shared__ _Float16 Ah[128 * 64], Bh[128 * 64];   // 16 KB each

    f32x4 acc[4][4];
#pragma unroll
    for (int i = 0; i < 4; ++i)
#pragma unroll
        for (int j = 0; j < 4; ++j) acc[i][j] = (f32x4){0.f, 0.f, 0.f, 0.f};

    for (int kt = 0; kt < Hn / 64; ++kt) {   // 16 K-steps of 64
        const int k0 = kt * 64;
        __syncthreads();   // compute(kt-1) reads done before overwrite
#pragma unroll
        for (int c = 0; c < 4; ++c) {
            const int idx = (wid * 4 + c) * 64 + lane;   // 16B chunk id, 0..1023
            const int row = idx >> 3;                    // 0..127
            const int cg  = (idx & 7) ^ (row & 7);       // swizzled global chunk
            glds16(&Xh[(size_t)(m0 + row) * Hn + k0 + cg * 8],
                   &Ah[(wid * 4 + c) * 512]);
            glds16(&WT[(size_t)(n0 + row) * Hn + k0 + cg * 8],
                   &Bh[(wid * 4 + c) * 512]);
        }
        __syncthreads();   // drains vmcnt(0): tile kt fully in LDS

#pragma unroll
        for (int kk = 0; kk < 2; ++kk) {
            h8 xa[4], wb[4];
#pragma unroll
            for (int t = 0; t < 4; ++t) {
                const int ar = wm * 64 + t * 16 + l16;
                const int br = wn * 64 + t * 16 + l16;
                xa[t] = *(const h8*)&Ah[ar * 64 + (((kk * 4 + quad) ^ (ar & 7)) * 8)];
                wb[t] = *(const h8*)&Bh[br * 64 + (((kk * 4 + quad) ^ (br & 7)) * 8)];
            }
            if (which < 2) {
#pragma unroll
                for (int i = 0; i < 4; ++i)
#pragma unroll
                    for (int j = 0; j < 4; ++j)
                        acc[i][j] = MFMA16F(xa[i], wb[j], acc[i][j]);
            } else {
#pragma unroll
                for (int i = 0; i < 4; ++i)
#pragma unroll
                    for (int j = 0; j < 4; ++j)
                        acc[i][j] = MFMA16F(wb[i], xa[j], acc[i][j]);
            }
        }
    }

    const float oscale = (which == 0) ? SCFULL : 1.0f;
    if (which < 2) {
        // D[m=quad*4+r][n=l16] -> [bh][s][d]
#pragma unroll
        for (int j = 0; j < 4; ++j) {
            const int n = n0 + wn * 64 + j * 16 + l16;
            const float bv = bias[n];
            const int hh = n >> 6, dd = n & 63;
#pragma unroll
            for (int i = 0; i < 4; ++i) {
                const int mb = m0 + wm * 64 + i * 16 + quad * 4;
#pragma unroll
                for (int r = 0; r < 4; ++r) {
                    const int m = mb + r;
                    const int b = m >> 11, s = m & (Sn - 1);
                    Dst[(((size_t)b * NHn + hh) * Sn + s) * DHn + dd] =
                        (_Float16)((acc[i][j][r] + bv) * oscale);
                }
            }
        }
    } else {
        // swapped: D rows = n-dim, cols = m-dim -> [bh][d][s]; x Wm[key=m]
        float wvj[4];
#pragma unroll
        for (int j = 0; j < 4; ++j)
            wvj[j] = (float)Wm[m0 + wm * 64 + j * 16 + l16];
#pragma unroll
        for (int i = 0; i < 4; ++i) {
#pragma unroll
            for (int r = 0; r < 4; ++r) {
                const int n = n0 + wn * 64 + i * 16 + quad * 4 + r;
                const float bv = bias[n];
                const int hh = n >> 6, dd = n & 63;
#pragma unroll
                for (int j = 0; j < 4; ++j) {
                    const int m = m0 + wm * 64 + j * 16 + l16;
                    const int b = m >> 11, s = m & (Sn - 1);
                    Dst[(((size_t)b * NHn + hh) * DHn + dd) * Sn + s] =
                        (_Float16)((acc[i][j][r] + bv) * wvj[j]);
                }
            }
        }
    }
}

// ---------------------------------------------------------------------------
// Flash attention (round-12 structure, UNCHANGED — best at 47.6us).
// ---------------------------------------------------------------------------
__global__ __launch_bounds__(256, 2) void attn(
    const _Float16* __restrict__ Qh, const _Float16* __restrict__ Kh,
    const _Float16* __restrict__ VTh, const _Float16* __restrict__ Wmg,
    float* __restrict__ Out)
{
    // --- XCD-grouping remap: 512 blocks, 8 XCDs, 4 bh per XCD ---
    const int flat = blockIdx.x + 16 * blockIdx.y + 256 * blockIdx.z;
    const int bh   = ((flat & 7) << 2) | ((flat >> 3) & 3);  // 0..31
    const int qb   = flat >> 5;                              // 0..15
    const int b = bh >> 4, h = bh & 15;

    const int tid  = threadIdx.x;
    const int wid  = tid >> 6;
    const int lane = tid & 63;
    const int l32  = lane & 31;
    const int hi   = lane >> 5;

    __shared__ __align__(16) _Float16 Kb[4][4096];  // [key][dim], swizzled
    __shared__ __align__(16) _Float16 Vb[4][4096];  // [dim][key], swizzled
    __shared__ __align__(16) _Float16 Wbs[Sn];      // full w row (4KB), once

    const int q0 = qb * 128 + wid * 32;

    const _Float16* Kg = Kh  + (size_t)bh * Sn * DHn;   // [key][dim]
    const _Float16* Vg = VTh + (size_t)bh * DHn * Sn;   // [dim][key]
    const _Float16* Wg = Wmg + (size_t)b * Sn;          // [key] weights

    // one-time W stage: 256 threads x 16B = 4KB (wave wid covers 512 elems)
    glds16(&Wg[(wid * 64 + lane) * 8], &Wbs[wid * 512]);

    const size_t qbase = ((size_t)bh * Sn + q0 + l32) * DHn;
    h8 qf[4];   // B-frag: B[k=dim][n=q=l32]
#pragma unroll
    for (int kd = 0; kd < 4; ++kd)
        qf[kd] = *(const h8*)&Qh[qbase + kd * 16 + hi * 8];

    asm volatile("s_waitcnt vmcnt(0)" ::: "memory");   // qf + W done, counter clean

    // stage one 64-key tile (4 glds16 per thread: K0,V0,K1,V1)
    auto stage = [&](int kt, int buf) {
        const int koff = kt * 64;
#pragma unroll
        for (int c = 0; c < 2; ++c) {
            const int idx = (wid * 2 + c) * 64 + lane;
            const int row = idx >> 3;
            const int cg  = (idx & 7) ^ (row & 7);
            glds16(&Kg[(size_t)(koff + row) * DHn + cg * 8],
                   &Kb[buf][(wid * 2 + c) * 512]);
            glds16(&Vg[(size_t)row * Sn + koff + cg * 8],
                   &Vb[buf][(wid * 2 + c) * 512]);
        }
    };

    stage(0, 0);
    stage(1, 1);

    f32x16 sA[2], sB[2], o[2], acc_l;
#pragma unroll
    for (int dt = 0; dt < 2; ++dt) o[dt] = (f32x16)(0.f);
    acc_l = (f32x16)(0.f);

    // D = K.Q^T for one 64-key tile -> s[2]; C init = 0
    auto qkt = [&](f32x16 (&s)[2], int buf) {
        __builtin_amdgcn_s_setprio(1);
#pragma unroll
        for (int t = 0; t < 2; ++t) {
            f32x16 c = (f32x16)(0.f);
#pragma unroll
            for (int kd = 0; kd < 4; ++kd) {
                const int row = t * 32 + l32;   // A-frag: A[m=key=row][k=dim]
                h8 kf = *(const h8*)&Kb[buf][row * 64 +
                                             (((kd * 2 + hi) ^ (row & 7)) * 8)];
                c = MFMA32F(kf, qf[kd], c);
            }
            s[t] = c;
        }
        __builtin_amdgcn_s_setprio(0);
    };

    // softmax from s, permlane exchange + PV + l-MFMA (w from one-time LDS)
    auto sm_pv = [&](f32x16 (&s)[2], int ktile, int buf) {
        unsigned int pk[2][4][2];
#pragma unroll
        for (int t = 0; t < 2; ++t) {
#pragma unroll
            for (int g = 0; g < 4; ++g) {
                const float p0 = __builtin_amdgcn_exp2f(s[t][g * 4 + 0]);
                const float p1 = __builtin_amdgcn_exp2f(s[t][g * 4 + 1]);
                const float p2 = __builtin_amdgcn_exp2f(s[t][g * 4 + 2]);
                const float p3 = __builtin_amdgcn_exp2f(s[t][g * 4 + 3]);
                H2PK u0, u1;
                u0.v = __builtin_amdgcn_cvt_pkrtz(p0, p1);
                u1.v = __builtin_amdgcn_cvt_pkrtz(p2, p3);
                pk[t][g][0] = u0.u;
                pk[t][g][1] = u1.u;
            }
        }

        __builtin_amdgcn_s_setprio(1);
#pragma unroll
        for (int ks = 0; ks < 4; ++ks) {
            const int t = ks >> 1, ge = (ks & 1) * 2;   // ge feeds dest hi=0
            u32x2 rA = __builtin_amdgcn_permlane32_swap(
                pk[t][ge][0], pk[t][ge + 1][0], false, false);
            u32x2 rB = __builtin_amdgcn_permlane32_swap(
                pk[t][ge][1], pk[t][ge + 1][1], false, false);
            U4H8 w;
            w.u[0] = rA[0]; w.u[1] = rB[0]; w.u[2] = rA[1]; w.u[3] = rB[1];
            // l: B[k][n] = w[key] broadcast over n
            h8 wv8 = *(const h8*)&Wbs[ktile * 64 + ks * 16 + hi * 8];
            acc_l = MFMA32F(w.v, wv8, acc_l);
#pragma unroll
            for (int dt = 0; dt < 2; ++dt) {
                const int row = dt * 32 + l32;   // B-frag: B[k=key][n=dim=row]
                h8 vf = *(const h8*)&Vb[buf][row * 64 +
                                             (((ks * 2 + hi) ^ (row & 7)) * 8)];
                o[dt] = MFMA32F(w.v, vf, o[dt]);
            }
        }
        __builtin_amdgcn_s_setprio(0);
    };

    // prologue: tile0 resident -> scores(0) into sA
    asm volatile("s_waitcnt vmcnt(4)" ::: "memory");
    __builtin_amdgcn_s_barrier();
    asm volatile("" ::: "memory");
    qkt(sA, 0);

    auto iter = [&](int kt, f32x16 (&scur)[2], f32x16 (&snxt)[2]) {
        stage(kt + 2, (kt + 2) & 3);
        asm volatile("s_waitcnt vmcnt(4)" ::: "memory");  // tile kt+1 landed
        __builtin_amdgcn_s_barrier();
        asm volatile("" ::: "memory");
        qkt(snxt, (kt + 1) & 3);       // MFMA, overlaps softmax below
        sm_pv(scur, kt, kt & 3);       // VALU + PV MFMA
    };

    for (int kt = 0; kt < 30; kt += 2) {
        iter(kt,     sA, sB);
        iter(kt + 1, sB, sA);
    }
    // kt = 30: no more staging; tile 31 needs full drain
    asm volatile("s_waitcnt vmcnt(0)" ::: "memory");
    __builtin_amdgcn_s_barrier();
    asm volatile("" ::: "memory");
    qkt(sB, 31 & 3);
    sm_pv(sA, 30, 30 & 3);
    sm_pv(sB, 31, 31 & 3);

    // ---- final: per-lane l (same C/D row mapping as o), normalize, store ----
#pragma unroll
    for (int g2 = 0; g2 < 4; ++g2) {
#pragma unroll
        for (int e = 0; e < 4; ++e) {
            const int r = g2 * 4 + e;
            const int q = q0 + 4 * hi + 8 * g2 + e;   // C/D row formula
            const size_t ob = ((size_t)b * Sn + q) * Hn + h * DHn;
            const float sc = 1.0f / acc_l[r];
#pragma unroll
            for (int dt = 0; dt < 2; ++dt)
                Out[ob + dt * 32 + l32] = o[dt][r] * sc;
        }
    }
}

extern "C" void kernel_launch(void* const* d_in, const int* in_sizes, int n_in,
                              void* d_out, int out_size, void* d_ws, size_t ws_size,
                              hipStream_t stream) {
    const float* X    = (const float*)d_in[0];
    const float* mask = (const float*)d_in[1];
    const float* Wq   = (const float*)d_in[2];
    const float* bq   = (const float*)d_in[3];
    const float* Wk   = (const float*)d_in[4];
    const float* bk   = (const float*)d_in[5];
    const float* Wv   = (const float*)d_in[6];
    const float* bv   = (const float*)d_in[7];
    float* out = (float*)d_out;

    const size_t NE = (size_t)Mn * Hn;         // 4M elements
    _Float16* Xh  = (_Float16*)d_ws;           // 8 MB
    _Float16* WT  = Xh + NE;                   // 3 x 2 MB
    _Float16* Qh  = WT + (size_t)3 * Hn * Hn;  // 8 MB
    _Float16* Kh  = Qh + NE;                   // 8 MB
    _Float16* VTh = Kh + NE;                   // 8 MB
    _Float16* Wm  = VTh + NE;                  // 4096 + 512 pad (glds overrun)

    prep<<<dim3(2048 + 768 + 1), dim3(256), 0, stream>>>(
        X, Wq, Wk, Wv, mask, Xh, WT, Wm);

    dim3 g1(Mn / 128, Hn / 128, 3), b1(256);
    qkv_mfma<<<g1, b1, 0, stream>>>(Xh, WT, bq, bk, bv, Wm, Qh, Kh, VTh);

    dim3 g2(Sn / 128, NHn, Bn), b2(256);
    attn<<<g2, b2, 0, stream>>>(Qh, Kh, VTh, Wm, out);
}